// Round 17
// baseline (375.902 us; speedup 1.0000x reference)
//
#include <hip/hip_runtime.h>
#include <math.h>

#define NN 50000
#define NE 800000
#define NB1 196
#define NTILES 25000      // NE/32
#define TT 7              // consecutive 32-edge tiles per chunk
#define EDGE_BLOCKS 1024  // 512 chunk-pairs x 2 dim-halves; 8 waves/block

typedef __attribute__((ext_vector_type(8))) short short8;
typedef __attribute__((ext_vector_type(4))) float f32x4;

__device__ __forceinline__ unsigned short f2bf(float f) {
    __bf16 b = (__bf16)f;
    return __builtin_bit_cast(unsigned short, b);
}

__device__ __forceinline__ short8 pack8(float4 a, float4 b) {
    short8 s;
    s[0] = (short)f2bf(a.x); s[1] = (short)f2bf(a.y);
    s[2] = (short)f2bf(a.z); s[3] = (short)f2bf(a.w);
    s[4] = (short)f2bf(b.x); s[5] = (short)f2bf(b.y);
    s[6] = (short)f2bf(b.z); s[7] = (short)f2bf(b.w);
    return s;
}

__device__ __forceinline__ int clampi(int v, int hi) {
    return v < 0 ? 0 : (v > hi ? hi : v);
}

__device__ __forceinline__ bool sniff_i64(const int* ei) {
    return ((ei[1] | ei[3] | ei[5] | ei[7] | ei[9] | ei[11] | ei[13] | ei[15]) == 0);
}

// ---- fused weight pack: W1 (w1-style) + W2 (w1-style, final GEMM) ----
__global__ void pack_weights_kernel(const float* __restrict__ W1, const float* __restrict__ W2,
                                    unsigned short* __restrict__ w1p, unsigned short* __restrict__ w2n) {
    int idx = blockIdx.x * 256 + threadIdx.x;
    if (idx < 320 * 128) {
        int e = idx & 7, lane = (idx >> 3) & 63, f = idx >> 9;
        int tm = f & 7, ks = f >> 3;
        int k = ks * 32 + 8 * (lane >> 4) + e;
        int n = tm * 16 + (lane & 15);
        w1p[idx] = f2bf(W1[k * 128 + n]);
    }
    if (idx < 128 * 128) {
        int e = idx & 7, lane = (idx >> 3) & 63, f = idx >> 9;
        int tn = f & 7, ks = f >> 3;
        int k = ks * 32 + 8 * (lane >> 4) + e;
        int n = tn * 16 + (lane & 15);
        w2n[idx] = f2bf(W2[k * 128 + n]);
    }
}

__global__ void pack_w1_kernel(const float* __restrict__ W1, unsigned short* __restrict__ outp) {
    int idx = blockIdx.x * 256 + threadIdx.x;
    if (idx >= 320 * 128) return;
    int e = idx & 7, lane = (idx >> 3) & 63, f = idx >> 9;
    int tm = f & 7, ks = f >> 3;
    int k = ks * 32 + 8 * (lane >> 4) + e;
    int n = tm * 16 + (lane & 15);
    outp[idx] = f2bf(W1[k * 128 + n]);
}

// W2 packed with GEMM2-matched k-map (fallback only)
__global__ void pack_w2_kernel(const float* __restrict__ W2, unsigned short* __restrict__ outp) {
    int idx = blockIdx.x * 256 + threadIdx.x;
    if (idx >= 128 * 128) return;
    int e = idx & 7, lane = (idx >> 3) & 63, f = idx >> 9;
    int tn = f & 7, ks2 = f >> 3;
    int k = (2 * ks2 + (e >> 2)) * 16 + 4 * (lane >> 4) + (e & 3);
    int n = tn * 16 + (lane & 15);
    outp[idx] = f2bf(W2[k * 128 + n]);
}

// fused prep: hbf = bf16(h); s(=d_out) = 0; G = 0; cnt = 0
__global__ void prep_kernel(const float4* __restrict__ h, ushort4* __restrict__ hbf,
                            float4* __restrict__ s, float* __restrict__ G,
                            int* __restrict__ cnt) {
    int i = blockIdx.x * 256 + threadIdx.x;
    int stride = gridDim.x * 256;
    for (int j = i; j < NN * 32; j += stride) {
        float4 f = h[j];
        ushort4 u;
        u.x = f2bf(f.x); u.y = f2bf(f.y); u.z = f2bf(f.z); u.w = f2bf(f.w);
        hbf[j] = u;
        s[j] = (float4){0.f, 0.f, 0.f, 0.f};
    }
    for (int j = i; j < NN; j += stride) { G[j] = 0.f; cnt[j] = 0; }
}

__global__ void copy_h_kernel(const float4* __restrict__ h, float4* __restrict__ outp) {
    int i = blockIdx.x * 256 + threadIdx.x;
    int stride = gridDim.x * 256;
    for (; i < NN * 32; i += stride) outp[i] = h[i];
}

// ---- destination-sort pipeline ----
__global__ void hist_kernel(const int* __restrict__ ei, int* __restrict__ cnt) {
    const bool i64 = sniff_i64(ei);
    const long long* ei64 = (const long long*)ei;
    for (int e = blockIdx.x * 256 + threadIdx.x; e < NE; e += gridDim.x * 256) {
        int r = i64 ? (int)ei64[e] : ei[e];
        r = clampi(r, NN - 1);
        atomicAdd(&cnt[r], 1);
    }
}

__global__ void scan1_kernel(const int* __restrict__ cnt, int* __restrict__ scanned,
                             int* __restrict__ bsum) {
    __shared__ int sm[256];
    int b = blockIdx.x, t = threadIdx.x, i = b * 256 + t;
    int c = (i < NN) ? cnt[i] : 0;
    sm[t] = c; __syncthreads();
#pragma unroll
    for (int d = 1; d < 256; d <<= 1) {
        int x = (t >= d) ? sm[t - d] : 0;
        __syncthreads();
        sm[t] += x;
        __syncthreads();
    }
    if (i < NN) scanned[i] = sm[t] - c;
    if (t == 255) bsum[b] = sm[255];
}

__global__ void scan2_kernel(const int* __restrict__ bsum, int* __restrict__ boff) {
    __shared__ int sm[256];
    int t = threadIdx.x;
    int c = (t < NB1) ? bsum[t] : 0;
    sm[t] = c; __syncthreads();
#pragma unroll
    for (int d = 1; d < 256; d <<= 1) {
        int x = (t >= d) ? sm[t - d] : 0;
        __syncthreads();
        sm[t] += x;
        __syncthreads();
    }
    if (t < NB1) boff[t] = sm[t] - c;
}

__global__ void scan3_kernel(const int* __restrict__ scanned, const int* __restrict__ boff,
                             int* __restrict__ cur) {
    int b = blockIdx.x, t = threadIdx.x, i = b * 256 + t;
    if (i < NN) cur[i] = scanned[i] + boff[b];
}

__global__ void scatter_kernel(const int* __restrict__ ei, int* __restrict__ cur,
                               int4* __restrict__ recs) {
    const bool i64 = sniff_i64(ei);
    const long long* ei64 = (const long long*)ei;
    for (int e = blockIdx.x * 256 + threadIdx.x; e < NE; e += gridDim.x * 256) {
        int r, c;
        if (i64) { r = (int)ei64[e]; c = (int)ei64[NE + e]; }
        else     { r = ei[e];        c = ei[NE + e]; }
        r = clampi(r, NN - 1);
        c = clampi(c, NN - 1);
        int pos = atomicAdd(&cur[r], 1);
        pos = clampi(pos, NE - 1);
        recs[pos] = make_int4(r, c, e, 0);
    }
}

// ---- edge kernel: tm-half wave specialization. Block pair (2p, 2p+1) processes the
// same edge chunks; hh=bid&1 selects output dims [hh*64, hh*64+64). Halves the
// accumulator (32 AGPR) AND the LDS (40 KB) to clear both occupancy limits. ----
__global__ __launch_bounds__(512) void edge_kernel_sorted(
    const unsigned short* __restrict__ hbf, const int4* __restrict__ recs,
    const float* __restrict__ bond, const float* __restrict__ b1v,
    const float* __restrict__ Wa, const float* __restrict__ bav,
    const short8* __restrict__ w1p, float* __restrict__ s, float* __restrict__ G)
{
    __shared__ short8 ldsW1[2560];   // 40 frag-columns (this half) = 40,960 B
    const int tid = threadIdx.x;
    const int hh = blockIdx.x & 1;   // dim-half
    // stage this half's W1 frags: local frag lf = ks*4+tm' -> global f = ks*8 + hh*4 + tm'
    for (int i = tid; i < 2560; i += 512) {
        int lf = i >> 6, lane_i = i & 63;
        int gf = (lf >> 2) * 8 + hh * 4 + (lf & 3);
        ldsW1[i] = w1p[gf * 64 + lane_i];
    }
    __syncthreads();

    const int lane = tid & 63;
    const int g = lane >> 4;
    const int m = lane & 15;
    const float baS = bav[0];

    int pr = blockIdx.x >> 1;                       // chunk-pair id 0..511
    pr = (pr & 7) * 64 + (pr >> 3);                 // XCD swizzle (twins stay adjacent)
    const int gw = pr * 8 + (tid >> 6);             // chunk id 0..4095
    const int t0 = gw * TT;
    int myT = NTILES - t0;
    if (myT > 0) {
        if (myT > TT) myT = TT;
        const int qst = 8 * myT;
        const int colBase = t0 * 32 + (m >> 2) * qst + (m & 3);
        const int dimb = hh * 64;

        int cn = -1;
        float cg = 0.f;
        float cv[4];
#pragma unroll
        for (int tm = 0; tm < 4; ++tm) cv[tm] = 0.f;

        for (int t = 0; t < myT; ++t) {
            int rA[2], cA[2], eO[2];
#pragma unroll
            for (int nt = 0; nt < 2; ++nt) {
                int4 rec = recs[colBase + t * 8 + nt * 4];
                rA[nt] = rec.x; cA[nt] = rec.y; eO[nt] = rec.z;
            }

            f32x4 acc1[4][2];
#pragma unroll
            for (int tm = 0; tm < 4; ++tm)
#pragma unroll
                for (int nt = 0; nt < 2; ++nt)
                    acc1[tm][nt] = (f32x4){0.f, 0.f, 0.f, 0.f};
            float gp[2] = {0.f, 0.f};

            // GEMM1 (half dims): hidden[edge][dimb..dimb+64)
#pragma unroll
            for (int ks = 0; ks < 10; ++ks) {
                short8 bf[2];
#pragma unroll
                for (int nt = 0; nt < 2; ++nt) {
                    if (ks < 8) {
                        int node = (ks < 4) ? rA[nt] : cA[nt];
                        const unsigned short* p = hbf + (long)node * 128 + (ks & 3) * 32 + 8 * g;
                        bf[nt] = *(const short8*)p;
                    } else {
                        const float* p = bond + (long)eO[nt] * 64 + (ks - 8) * 32 + 8 * g;
                        float4 f0 = *(const float4*)(p);
                        float4 f1 = *(const float4*)(p + 4);
                        bf[nt] = pack8(f0, f1);
                        const float* wap = Wa + (ks - 8) * 32 + 8 * g;
                        float4 w0 = *(const float4*)(wap);
                        float4 w1q = *(const float4*)(wap + 4);
                        gp[nt] += f0.x * w0.x + f0.y * w0.y + f0.z * w0.z + f0.w * w0.w
                                + f1.x * w1q.x + f1.y * w1q.y + f1.z * w1q.z + f1.w * w1q.w;
                    }
                }
#pragma unroll
                for (int tm = 0; tm < 4; ++tm) {
                    short8 wfrag = ldsW1[(ks * 4 + tm) * 64 + lane];
                    acc1[tm][0] = __builtin_amdgcn_mfma_f32_16x16x32_bf16(bf[0], wfrag, acc1[tm][0], 0, 0, 0);
                    acc1[tm][1] = __builtin_amdgcn_mfma_f32_16x16x32_bf16(bf[1], wfrag, acc1[tm][1], 0, 0, 0);
                }
            }

            float gate[2];
#pragma unroll
            for (int nt = 0; nt < 2; ++nt) {
                float ssum = gp[nt];
                ssum += __shfl_xor(ssum, 16);
                ssum += __shfl_xor(ssum, 32);
                gate[nt] = 1.f / (1.f + expf(-(ssum + baS)));
            }

            // carry-fold epilogue (half dims)
#pragma unroll
            for (int nt = 0; nt < 2; ++nt) {
#pragma unroll
                for (int r = 0; r < 4; ++r) {
                    int nd = __shfl(rA[nt], 4 * g + r);
                    float gr = __shfl(gate[nt], 4 * g + r);
                    if (nd == cn) {
#pragma unroll
                        for (int tm = 0; tm < 4; ++tm)
                            cv[tm] += fmaxf(acc1[tm][nt][r] + b1v[dimb + tm * 16 + m], 0.f) * gr;
                        cg += gr;
                    } else {
                        if (cn >= 0) {
#pragma unroll
                            for (int tm = 0; tm < 4; ++tm)
                                atomicAdd(s + (long)cn * 128 + dimb + tm * 16 + m, cv[tm]);
                            if (hh == 0 && m == 0) atomicAdd(G + cn, cg);
                        }
                        cn = nd;
#pragma unroll
                        for (int tm = 0; tm < 4; ++tm)
                            cv[tm] = fmaxf(acc1[tm][nt][r] + b1v[dimb + tm * 16 + m], 0.f) * gr;
                        cg = gr;
                    }
                }
            }
        }

        if (cn >= 0) {
#pragma unroll
            for (int tm = 0; tm < 4; ++tm)
                atomicAdd(s + (long)cn * 128 + dimb + tm * 16 + m, cv[tm]);
            if (hh == 0 && m == 0) atomicAdd(G + cn, cg);
        }
    }
}

// ---- final (MFMA): out = h + (bf16)s @ W2 + G*b2, one wave per 16 nodes, in-place ----
__global__ __launch_bounds__(256) void final_mfma_kernel(
    const float* __restrict__ h, const float* __restrict__ G,
    const float* __restrict__ b2v, const short8* __restrict__ w2n,
    float* __restrict__ sout)
{
    const int tid = threadIdx.x;
    const int lane = tid & 63;
    const int g = lane >> 4;
    const int m = lane & 15;
    const int wtile = blockIdx.x * 4 + (tid >> 6);
    if (wtile >= NN / 16) return;
    const int n0 = wtile * 16;

    f32x4 acc[8];
#pragma unroll
    for (int tn = 0; tn < 8; ++tn) {
#pragma unroll
        for (int r = 0; r < 4; ++r) {
            int n = n0 + 4 * g + r;
            int d = tn * 16 + m;
            acc[tn][r] = h[(long)n * 128 + d] + G[n] * b2v[d];
        }
    }

#pragma unroll
    for (int ks = 0; ks < 4; ++ks) {
        const float* sp = sout + (long)(n0 + m) * 128 + ks * 32 + 8 * g;
        float4 f0 = *(const float4*)(sp);
        float4 f1 = *(const float4*)(sp + 4);
        short8 a = pack8(f0, f1);
#pragma unroll
        for (int tn = 0; tn < 8; ++tn)
            acc[tn] = __builtin_amdgcn_mfma_f32_16x16x32_bf16(a, w2n[(ks * 8 + tn) * 64 + lane], acc[tn], 0, 0, 0);
    }

#pragma unroll
    for (int tn = 0; tn < 8; ++tn)
#pragma unroll
        for (int r = 0; r < 4; ++r)
            sout[(long)(n0 + 4 * g + r) * 128 + tn * 16 + m] = acc[tn][r];
}

// ---- fallback (unsorted, fp32 h, per-edge full MLP, atomics) if ws too small ----
__global__ __launch_bounds__(512) void edge_kernel_unsorted(
    const float* __restrict__ h, const int* __restrict__ ei,
    const float* __restrict__ bond, const float* __restrict__ b1v,
    const float* __restrict__ b2v, const float* __restrict__ Wa,
    const float* __restrict__ bav, const short8* __restrict__ w1p,
    const short8* __restrict__ w2p, float* __restrict__ outp)
{
    __shared__ short8 ldsW1[5120];
    const int tid = threadIdx.x;
#pragma unroll
    for (int i = 0; i < 10; ++i) ldsW1[tid + i * 512] = w1p[tid + i * 512];
    __syncthreads();

    const int lane = tid & 63;
    const int g = lane >> 4;
    const int m = lane & 15;
    const float baS = bav[0];
    const long long* ei64 = (const long long*)ei;
    const bool i64 = sniff_i64(ei);

    const int gw = blockIdx.x * 8 + (tid >> 6);
    const int nw = gridDim.x * 8;
    for (int tile = gw; tile < NE / 32; tile += nw) {
        const int eb = tile * 32;
        int eIdx[2], rA[2], cA[2];
#pragma unroll
        for (int nt = 0; nt < 2; ++nt) {
            eIdx[nt] = eb + nt * 16 + m;
            if (i64) { rA[nt] = (int)ei64[eIdx[nt]]; cA[nt] = (int)ei64[NE + eIdx[nt]]; }
            else     { rA[nt] = ei[eIdx[nt]];        cA[nt] = ei[NE + eIdx[nt]]; }
            rA[nt] = clampi(rA[nt], NN - 1);
            cA[nt] = clampi(cA[nt], NN - 1);
        }
        f32x4 acc1[8][2];
#pragma unroll
        for (int tm = 0; tm < 8; ++tm)
#pragma unroll
            for (int nt = 0; nt < 2; ++nt) acc1[tm][nt] = (f32x4){0.f,0.f,0.f,0.f};
        float gp[2] = {0.f, 0.f};
#pragma unroll
        for (int ks = 0; ks < 10; ++ks) {
            short8 bf[2];
#pragma unroll
            for (int nt = 0; nt < 2; ++nt) {
                const float* p;
                if (ks < 4)      p = h + (long)rA[nt] * 128 + ks * 32;
                else if (ks < 8) p = h + (long)cA[nt] * 128 + (ks - 4) * 32;
                else             p = bond + (long)eIdx[nt] * 64 + (ks - 8) * 32;
                float4 f0 = *(const float4*)(p + 8 * g);
                float4 f1 = *(const float4*)(p + 8 * g + 4);
                bf[nt] = pack8(f0, f1);
                if (ks >= 8) {
                    const float* wap = Wa + (ks - 8) * 32 + 8 * g;
                    float4 w0 = *(const float4*)(wap);
                    float4 w1q = *(const float4*)(wap + 4);
                    gp[nt] += f0.x * w0.x + f0.y * w0.y + f0.z * w0.z + f0.w * w0.w
                            + f1.x * w1q.x + f1.y * w1q.y + f1.z * w1q.z + f1.w * w1q.w;
                }
            }
#pragma unroll
            for (int tm = 0; tm < 8; ++tm) {
                short8 a = ldsW1[(ks * 8 + tm) * 64 + lane];
                acc1[tm][0] = __builtin_amdgcn_mfma_f32_16x16x32_bf16(a, bf[0], acc1[tm][0], 0, 0, 0);
                acc1[tm][1] = __builtin_amdgcn_mfma_f32_16x16x32_bf16(a, bf[1], acc1[tm][1], 0, 0, 0);
            }
        }
        float gate[2];
#pragma unroll
        for (int nt = 0; nt < 2; ++nt) {
            float ssum = gp[nt];
            ssum += __shfl_xor(ssum, 16);
            ssum += __shfl_xor(ssum, 32);
            gate[nt] = 1.f / (1.f + expf(-(ssum + baS)));
        }
        short8 pf[4][2];
#pragma unroll
        for (int ks2 = 0; ks2 < 4; ++ks2) {
            float4 c0 = *(const float4*)(b1v + (2 * ks2) * 16 + 4 * g);
            float4 c1 = *(const float4*)(b1v + (2 * ks2 + 1) * 16 + 4 * g);
#pragma unroll
            for (int nt = 0; nt < 2; ++nt) {
                float4 lo, hi;
                lo.x = fmaxf(acc1[2*ks2][nt][0] + c0.x, 0.f);
                lo.y = fmaxf(acc1[2*ks2][nt][1] + c0.y, 0.f);
                lo.z = fmaxf(acc1[2*ks2][nt][2] + c0.z, 0.f);
                lo.w = fmaxf(acc1[2*ks2][nt][3] + c0.w, 0.f);
                hi.x = fmaxf(acc1[2*ks2+1][nt][0] + c1.x, 0.f);
                hi.y = fmaxf(acc1[2*ks2+1][nt][1] + c1.y, 0.f);
                hi.z = fmaxf(acc1[2*ks2+1][nt][2] + c1.z, 0.f);
                hi.w = fmaxf(acc1[2*ks2+1][nt][3] + c1.w, 0.f);
                pf[ks2][nt] = pack8(lo, hi);
            }
        }
        f32x4 acc2[8][2];
#pragma unroll
        for (int tn = 0; tn < 8; ++tn)
#pragma unroll
            for (int nt = 0; nt < 2; ++nt) acc2[tn][nt] = (f32x4){0.f,0.f,0.f,0.f};
#pragma unroll
        for (int ks2 = 0; ks2 < 4; ++ks2) {
#pragma unroll
            for (int tn = 0; tn < 8; ++tn) {
                short8 ww = w2p[(ks2 * 8 + tn) * 64 + lane];
                acc2[tn][0] = __builtin_amdgcn_mfma_f32_16x16x32_bf16(pf[ks2][0], ww, acc2[tn][0], 0, 0, 0);
                acc2[tn][1] = __builtin_amdgcn_mfma_f32_16x16x32_bf16(pf[ks2][1], ww, acc2[tn][1], 0, 0, 0);
            }
        }
#pragma unroll
        for (int nt = 0; nt < 2; ++nt) {
            int nodeR[4]; float gt[4];
#pragma unroll
            for (int r = 0; r < 4; ++r) {
                nodeR[r] = __shfl(rA[nt], 4 * g + r);
                gt[r] = __shfl(gate[nt], 4 * g + r);
            }
#pragma unroll
            for (int tn = 0; tn < 8; ++tn) {
                float c2 = b2v[tn * 16 + m];
#pragma unroll
                for (int r = 0; r < 4; ++r) {
                    float vv = (acc2[tn][nt][r] + c2) * gt[r];
                    atomicAdd(outp + (long)nodeR[r] * 128 + tn * 16 + m, vv);
                }
            }
        }
    }
}

extern "C" void kernel_launch(void* const* d_in, const int* in_sizes, int n_in,
                              void* d_out, int out_size, void* d_ws, size_t ws_size,
                              hipStream_t stream) {
    const float* h    = (const float*)d_in[0];
    const int*   ei   = (const int*)d_in[1];
    const float* bond = (const float*)d_in[2];
    const float* W1   = (const float*)d_in[3];
    const float* b1   = (const float*)d_in[4];
    const float* W2   = (const float*)d_in[5];
    const float* b2   = (const float*)d_in[6];
    const float* Wa   = (const float*)d_in[7];
    const float* ba   = (const float*)d_in[8];
    float* outp = (float*)d_out;

    char* ws = (char*)d_ws;
    const size_t o_w1  = 0;            // 81920
    const size_t o_w2  = 81920;        // 32768 (w2n main / w2p fallback)
    const size_t o_hbf = 114688;       // 12,800,000
    const size_t o_cnt = 12914688;     // 200,000
    const size_t o_scn = 13114688;     // 200,000 (aliased as G after scan3)
    const size_t o_bs  = 13314688;     // 1,024
    const size_t o_bo  = 13315712;     // 1,024
    const size_t o_cur = 13316736;     // 200,000
    const size_t o_rec = 13516736;     // 12,800,000
    const size_t need  = 26316736;

    unsigned short* w1p = (unsigned short*)(ws + o_w1);
    unsigned short* w2p = (unsigned short*)(ws + o_w2);

    if (ws_size >= need) {
        unsigned short* hbf = (unsigned short*)(ws + o_hbf);
        int* cnt = (int*)(ws + o_cnt);
        int* scn = (int*)(ws + o_scn);
        int* bs  = (int*)(ws + o_bs);
        int* bo  = (int*)(ws + o_bo);
        int* cur = (int*)(ws + o_cur);
        int4* recs = (int4*)(ws + o_rec);
        float* G = (float*)(ws + o_scn);   // alias: scn dead after scan3

        hipLaunchKernelGGL(pack_weights_kernel, dim3(160), dim3(256), 0, stream, W1, W2, w1p, w2p);
        hipLaunchKernelGGL(prep_kernel, dim3(2048), dim3(256), 0, stream,
                           (const float4*)h, (ushort4*)hbf, (float4*)outp, G, cnt);
        hipLaunchKernelGGL(hist_kernel, dim3(1024), dim3(256), 0, stream, ei, cnt);
        hipLaunchKernelGGL(scan1_kernel, dim3(NB1), dim3(256), 0, stream, cnt, scn, bs);
        hipLaunchKernelGGL(scan2_kernel, dim3(1), dim3(256), 0, stream, bs, bo);
        hipLaunchKernelGGL(scan3_kernel, dim3(NB1), dim3(256), 0, stream, scn, bo, cur);
        hipLaunchKernelGGL(scatter_kernel, dim3(1024), dim3(256), 0, stream, ei, cur, recs);
        hipLaunchKernelGGL(edge_kernel_sorted, dim3(EDGE_BLOCKS), dim3(512), 0, stream,
                           hbf, recs, bond, b1, Wa, ba,
                           (const short8*)w1p, outp, G);
        hipLaunchKernelGGL(final_mfma_kernel, dim3((NN / 16 + 3) / 4), dim3(256), 0, stream,
                           h, G, b2, (const short8*)w2p, outp);
    } else {
        hipLaunchKernelGGL(pack_w1_kernel, dim3(160), dim3(256), 0, stream, W1, w1p);
        hipLaunchKernelGGL(pack_w2_kernel, dim3(64), dim3(256), 0, stream, W2, w2p);
        hipLaunchKernelGGL(copy_h_kernel, dim3(1600), dim3(256), 0, stream,
                           (const float4*)h, (float4*)outp);
        hipLaunchKernelGGL(edge_kernel_unsorted, dim3(512), dim3(512), 0, stream,
                           h, ei, bond, b1, b2, Wa, ba,
                           (const short8*)w1p, (const short8*)w2p, outp);
    }
}

// Round 18
// 246.833 us; speedup vs baseline: 1.5229x; 1.5229x over previous
//
#include <hip/hip_runtime.h>
#include <math.h>

#define NN 50000
#define NE 800000
#define NB1 196
#define NTILES 25000      // NE/32
#define TT 7              // consecutive tiles per wave
#define EDGE_BLOCKS 512   // 512 blocks * 8 waves = 4096 waves; 3572 busy
#define LDSF 64           // W1 frag-columns in LDS = 65,536 B (r13 best config)

typedef __attribute__((ext_vector_type(8))) short short8;
typedef __attribute__((ext_vector_type(4))) float f32x4;

__device__ __forceinline__ unsigned short f2bf(float f) {
    __bf16 b = (__bf16)f;
    return __builtin_bit_cast(unsigned short, b);
}

__device__ __forceinline__ short8 pack8(float4 a, float4 b) {
    short8 s;
    s[0] = (short)f2bf(a.x); s[1] = (short)f2bf(a.y);
    s[2] = (short)f2bf(a.z); s[3] = (short)f2bf(a.w);
    s[4] = (short)f2bf(b.x); s[5] = (short)f2bf(b.y);
    s[6] = (short)f2bf(b.z); s[7] = (short)f2bf(b.w);
    return s;
}

__device__ __forceinline__ int clampi(int v, int hi) {
    return v < 0 ? 0 : (v > hi ? hi : v);
}

__device__ __forceinline__ bool sniff_i64(const int* ei) {
    return ((ei[1] | ei[3] | ei[5] | ei[7] | ei[9] | ei[11] | ei[13] | ei[15]) == 0);
}

// ---- fused weight pack: W1 (w1-style) + W2 (w1-style, final GEMM) ----
__global__ void pack_weights_kernel(const float* __restrict__ W1, const float* __restrict__ W2,
                                    unsigned short* __restrict__ w1p, unsigned short* __restrict__ w2n) {
    int idx = blockIdx.x * 256 + threadIdx.x;
    if (idx < 320 * 128) {
        int e = idx & 7, lane = (idx >> 3) & 63, f = idx >> 9;
        int tm = f & 7, ks = f >> 3;
        int k = ks * 32 + 8 * (lane >> 4) + e;
        int n = tm * 16 + (lane & 15);
        w1p[idx] = f2bf(W1[k * 128 + n]);
    }
    if (idx < 128 * 128) {
        int e = idx & 7, lane = (idx >> 3) & 63, f = idx >> 9;
        int tn = f & 7, ks = f >> 3;
        int k = ks * 32 + 8 * (lane >> 4) + e;
        int n = tn * 16 + (lane & 15);
        w2n[idx] = f2bf(W2[k * 128 + n]);
    }
}

__global__ void pack_w1_kernel(const float* __restrict__ W1, unsigned short* __restrict__ outp) {
    int idx = blockIdx.x * 256 + threadIdx.x;
    if (idx >= 320 * 128) return;
    int e = idx & 7, lane = (idx >> 3) & 63, f = idx >> 9;
    int tm = f & 7, ks = f >> 3;
    int k = ks * 32 + 8 * (lane >> 4) + e;
    int n = tm * 16 + (lane & 15);
    outp[idx] = f2bf(W1[k * 128 + n]);
}

// W2 packed with GEMM2-matched k-map (fallback only)
__global__ void pack_w2_kernel(const float* __restrict__ W2, unsigned short* __restrict__ outp) {
    int idx = blockIdx.x * 256 + threadIdx.x;
    if (idx >= 128 * 128) return;
    int e = idx & 7, lane = (idx >> 3) & 63, f = idx >> 9;
    int tn = f & 7, ks2 = f >> 3;
    int k = (2 * ks2 + (e >> 2)) * 16 + 4 * (lane >> 4) + (e & 3);
    int n = tn * 16 + (lane & 15);
    outp[idx] = f2bf(W2[k * 128 + n]);
}

// fused prep: hbf = bf16(h); s(=d_out) = 0; G = 0; cnt = 0
__global__ void prep_kernel(const float4* __restrict__ h, ushort4* __restrict__ hbf,
                            float4* __restrict__ s, float* __restrict__ G,
                            int* __restrict__ cnt) {
    int i = blockIdx.x * 256 + threadIdx.x;
    int stride = gridDim.x * 256;
    for (int j = i; j < NN * 32; j += stride) {
        float4 f = h[j];
        ushort4 u;
        u.x = f2bf(f.x); u.y = f2bf(f.y); u.z = f2bf(f.z); u.w = f2bf(f.w);
        hbf[j] = u;
        s[j] = (float4){0.f, 0.f, 0.f, 0.f};
    }
    for (int j = i; j < NN; j += stride) { G[j] = 0.f; cnt[j] = 0; }
}

__global__ void copy_h_kernel(const float4* __restrict__ h, float4* __restrict__ outp) {
    int i = blockIdx.x * 256 + threadIdx.x;
    int stride = gridDim.x * 256;
    for (; i < NN * 32; i += stride) outp[i] = h[i];
}

// ---- destination-sort pipeline ----
__global__ void hist_kernel(const int* __restrict__ ei, int* __restrict__ cnt) {
    const bool i64 = sniff_i64(ei);
    const long long* ei64 = (const long long*)ei;
    for (int e = blockIdx.x * 256 + threadIdx.x; e < NE; e += gridDim.x * 256) {
        int r = i64 ? (int)ei64[e] : ei[e];
        r = clampi(r, NN - 1);
        atomicAdd(&cnt[r], 1);
    }
}

__global__ void scan1_kernel(const int* __restrict__ cnt, int* __restrict__ scanned,
                             int* __restrict__ bsum) {
    __shared__ int sm[256];
    int b = blockIdx.x, t = threadIdx.x, i = b * 256 + t;
    int c = (i < NN) ? cnt[i] : 0;
    sm[t] = c; __syncthreads();
#pragma unroll
    for (int d = 1; d < 256; d <<= 1) {
        int x = (t >= d) ? sm[t - d] : 0;
        __syncthreads();
        sm[t] += x;
        __syncthreads();
    }
    if (i < NN) scanned[i] = sm[t] - c;
    if (t == 255) bsum[b] = sm[255];
}

__global__ void scan2_kernel(const int* __restrict__ bsum, int* __restrict__ boff) {
    __shared__ int sm[256];
    int t = threadIdx.x;
    int c = (t < NB1) ? bsum[t] : 0;
    sm[t] = c; __syncthreads();
#pragma unroll
    for (int d = 1; d < 256; d <<= 1) {
        int x = (t >= d) ? sm[t - d] : 0;
        __syncthreads();
        sm[t] += x;
        __syncthreads();
    }
    if (t < NB1) boff[t] = sm[t] - c;
}

__global__ void scan3_kernel(const int* __restrict__ scanned, const int* __restrict__ boff,
                             int* __restrict__ cur) {
    int b = blockIdx.x, t = threadIdx.x, i = b * 256 + t;
    if (i < NN) cur[i] = scanned[i] + boff[b];
}

__global__ void scatter_kernel(const int* __restrict__ ei, int* __restrict__ cur,
                               int4* __restrict__ recs) {
    const bool i64 = sniff_i64(ei);
    const long long* ei64 = (const long long*)ei;
    for (int e = blockIdx.x * 256 + threadIdx.x; e < NE; e += gridDim.x * 256) {
        int r, c;
        if (i64) { r = (int)ei64[e]; c = (int)ei64[NE + e]; }
        else     { r = ei[e];        c = ei[NE + e]; }
        r = clampi(r, NN - 1);
        c = clampi(c, NN - 1);
        int pos = atomicAdd(&cur[r], 1);
        pos = clampi(pos, NE - 1);
        recs[pos] = make_int4(r, c, e, 0);
    }
}

// ---- edge kernel (r13-exact): GEMM1 swapped, contiguous 7-tile chunks per wave,
// cross-tile carry-fold into s (atomic only on node change) + G ----
__global__ __launch_bounds__(512) void edge_kernel_sorted(
    const unsigned short* __restrict__ hbf, const int4* __restrict__ recs,
    const float* __restrict__ bond, const float* __restrict__ b1v,
    const float* __restrict__ Wa, const float* __restrict__ bav,
    const short8* __restrict__ w1p, float* __restrict__ s, float* __restrict__ G)
{
    __shared__ short8 ldsW1[LDSF * 64];   // 64 frags = 65,536 B (r13 best)
    const int tid = threadIdx.x;
    for (int i = tid; i < LDSF * 64; i += 512) ldsW1[i] = w1p[i];
    __syncthreads();

    const int lane = tid & 63;
    const int g = lane >> 4;
    const int m = lane & 15;
    const float baS = bav[0];

    int bid = blockIdx.x;
    bid = (bid & 7) * (EDGE_BLOCKS / 8) + (bid >> 3);  // XCD swizzle (512%8==0, bijective)
    const int gw = bid * 8 + (tid >> 6);
    const int t0 = gw * TT;
    int myT = NTILES - t0;
    if (myT > 0) {
        if (myT > TT) myT = TT;
        const long wbase = (long)t0 * 32;
        const int qst = 8 * myT;
        const long colBase = wbase + (long)(m >> 2) * qst + (m & 3);

        int cn = -1;
        float cg = 0.f;
        float cv[8];
#pragma unroll
        for (int tm = 0; tm < 8; ++tm) cv[tm] = 0.f;

        for (int t = 0; t < myT; ++t) {
            int rA[2], cA[2], eO[2];
#pragma unroll
            for (int nt = 0; nt < 2; ++nt) {
                int4 rec = recs[colBase + t * 8 + nt * 4];
                rA[nt] = clampi(rec.x, NN - 1);
                cA[nt] = clampi(rec.y, NN - 1);
                eO[nt] = clampi(rec.z, NE - 1);
            }

            f32x4 acc1[8][2];
#pragma unroll
            for (int tm = 0; tm < 8; ++tm)
#pragma unroll
                for (int nt = 0; nt < 2; ++nt)
                    acc1[tm][nt] = (f32x4){0.f, 0.f, 0.f, 0.f};
            float gp[2] = {0.f, 0.f};

            // GEMM1: hidden[edge][dim] = x @ W1 via mfma(A=x_frag, B=W1_frag)
#pragma unroll
            for (int ks = 0; ks < 10; ++ks) {
                short8 bf[2];
#pragma unroll
                for (int nt = 0; nt < 2; ++nt) {
                    if (ks < 8) {
                        int node = (ks < 4) ? rA[nt] : cA[nt];
                        const unsigned short* p = hbf + (long)node * 128 + (ks & 3) * 32 + 8 * g;
                        bf[nt] = *(const short8*)p;
                    } else {
                        const float* p = bond + (long)eO[nt] * 64 + (ks - 8) * 32 + 8 * g;
                        float4 f0 = *(const float4*)(p);
                        float4 f1 = *(const float4*)(p + 4);
                        bf[nt] = pack8(f0, f1);
                        const float* wap = Wa + (ks - 8) * 32 + 8 * g;
                        float4 w0 = *(const float4*)(wap);
                        float4 w1q = *(const float4*)(wap + 4);
                        gp[nt] += f0.x * w0.x + f0.y * w0.y + f0.z * w0.z + f0.w * w0.w
                                + f1.x * w1q.x + f1.y * w1q.y + f1.z * w1q.z + f1.w * w1q.w;
                    }
                }
#pragma unroll
                for (int tm = 0; tm < 8; ++tm) {
                    const int f = ks * 8 + tm;
                    short8 wfrag = (f < LDSF) ? ldsW1[f * 64 + lane] : w1p[f * 64 + lane];
                    acc1[tm][0] = __builtin_amdgcn_mfma_f32_16x16x32_bf16(bf[0], wfrag, acc1[tm][0], 0, 0, 0);
                    acc1[tm][1] = __builtin_amdgcn_mfma_f32_16x16x32_bf16(bf[1], wfrag, acc1[tm][1], 0, 0, 0);
                }
            }

            float gate[2];
#pragma unroll
            for (int nt = 0; nt < 2; ++nt) {
                float ssum = gp[nt];
                ssum += __shfl_xor(ssum, 16);
                ssum += __shfl_xor(ssum, 32);
                gate[nt] = 1.f / (1.f + expf(-(ssum + baS)));
            }

            // carry-fold epilogue: quarter g's edges contiguous & sorted over (t,nt,r)
#pragma unroll
            for (int nt = 0; nt < 2; ++nt) {
#pragma unroll
                for (int r = 0; r < 4; ++r) {
                    int nd = __shfl(rA[nt], 4 * g + r);
                    float gr = __shfl(gate[nt], 4 * g + r);
                    if (nd == cn) {
#pragma unroll
                        for (int tm = 0; tm < 8; ++tm)
                            cv[tm] += fmaxf(acc1[tm][nt][r] + b1v[tm * 16 + m], 0.f) * gr;
                        cg += gr;
                    } else {
                        if (cn >= 0) {
#pragma unroll
                            for (int tm = 0; tm < 8; ++tm)
                                atomicAdd(s + (long)cn * 128 + tm * 16 + m, cv[tm]);
                            if (m == 0) atomicAdd(G + cn, cg);
                        }
                        cn = nd;
#pragma unroll
                        for (int tm = 0; tm < 8; ++tm)
                            cv[tm] = fmaxf(acc1[tm][nt][r] + b1v[tm * 16 + m], 0.f) * gr;
                        cg = gr;
                    }
                }
            }
        }

        if (cn >= 0) {
#pragma unroll
            for (int tm = 0; tm < 8; ++tm)
                atomicAdd(s + (long)cn * 128 + tm * 16 + m, cv[tm]);
            if (m == 0) atomicAdd(G + cn, cg);
        }
    }
}

// ---- final (MFMA): out = h + (bf16)s @ W2 + G*b2, one wave per 16 nodes, in-place ----
__global__ __launch_bounds__(256) void final_mfma_kernel(
    const float* __restrict__ h, const float* __restrict__ G,
    const float* __restrict__ b2v, const short8* __restrict__ w2n,
    float* __restrict__ sout)
{
    const int tid = threadIdx.x;
    const int lane = tid & 63;
    const int g = lane >> 4;
    const int m = lane & 15;
    const int wtile = blockIdx.x * 4 + (tid >> 6);
    if (wtile >= NN / 16) return;
    const int n0 = wtile * 16;

    f32x4 acc[8];
#pragma unroll
    for (int tn = 0; tn < 8; ++tn) {
#pragma unroll
        for (int r = 0; r < 4; ++r) {
            int n = n0 + 4 * g + r;
            int d = tn * 16 + m;
            acc[tn][r] = h[(long)n * 128 + d] + G[n] * b2v[d];
        }
    }

#pragma unroll
    for (int ks = 0; ks < 4; ++ks) {
        const float* sp = sout + (long)(n0 + m) * 128 + ks * 32 + 8 * g;
        float4 f0 = *(const float4*)(sp);
        float4 f1 = *(const float4*)(sp + 4);
        short8 a = pack8(f0, f1);
#pragma unroll
        for (int tn = 0; tn < 8; ++tn)
            acc[tn] = __builtin_amdgcn_mfma_f32_16x16x32_bf16(a, w2n[(ks * 8 + tn) * 64 + lane], acc[tn], 0, 0, 0);
    }

#pragma unroll
    for (int tn = 0; tn < 8; ++tn)
#pragma unroll
        for (int r = 0; r < 4; ++r)
            sout[(long)(n0 + 4 * g + r) * 128 + tn * 16 + m] = acc[tn][r];
}

// ---- fallback (unsorted, fp32 h, per-edge full MLP, atomics) if ws too small ----
__global__ __launch_bounds__(512) void edge_kernel_unsorted(
    const float* __restrict__ h, const int* __restrict__ ei,
    const float* __restrict__ bond, const float* __restrict__ b1v,
    const float* __restrict__ b2v, const float* __restrict__ Wa,
    const float* __restrict__ bav, const short8* __restrict__ w1p,
    const short8* __restrict__ w2p, float* __restrict__ outp)
{
    __shared__ short8 ldsW1[5120];
    const int tid = threadIdx.x;
#pragma unroll
    for (int i = 0; i < 10; ++i) ldsW1[tid + i * 512] = w1p[tid + i * 512];
    __syncthreads();

    const int lane = tid & 63;
    const int g = lane >> 4;
    const int m = lane & 15;
    const float baS = bav[0];
    const long long* ei64 = (const long long*)ei;
    const bool i64 = sniff_i64(ei);

    const int gw = blockIdx.x * 8 + (tid >> 6);
    const int nw = gridDim.x * 8;
    for (int tile = gw; tile < NE / 32; tile += nw) {
        const int eb = tile * 32;
        int eIdx[2], rA[2], cA[2];
#pragma unroll
        for (int nt = 0; nt < 2; ++nt) {
            eIdx[nt] = eb + nt * 16 + m;
            if (i64) { rA[nt] = (int)ei64[eIdx[nt]]; cA[nt] = (int)ei64[NE + eIdx[nt]]; }
            else     { rA[nt] = ei[eIdx[nt]];        cA[nt] = ei[NE + eIdx[nt]]; }
            rA[nt] = clampi(rA[nt], NN - 1);
            cA[nt] = clampi(cA[nt], NN - 1);
        }
        f32x4 acc1[8][2];
#pragma unroll
        for (int tm = 0; tm < 8; ++tm)
#pragma unroll
            for (int nt = 0; nt < 2; ++nt) acc1[tm][nt] = (f32x4){0.f,0.f,0.f,0.f};
        float gp[2] = {0.f, 0.f};
#pragma unroll
        for (int ks = 0; ks < 10; ++ks) {
            short8 bf[2];
#pragma unroll
            for (int nt = 0; nt < 2; ++nt) {
                const float* p;
                if (ks < 4)      p = h + (long)rA[nt] * 128 + ks * 32;
                else if (ks < 8) p = h + (long)cA[nt] * 128 + (ks - 4) * 32;
                else             p = bond + (long)eIdx[nt] * 64 + (ks - 8) * 32;
                float4 f0 = *(const float4*)(p + 8 * g);
                float4 f1 = *(const float4*)(p + 8 * g + 4);
                bf[nt] = pack8(f0, f1);
                if (ks >= 8) {
                    const float* wap = Wa + (ks - 8) * 32 + 8 * g;
                    float4 w0 = *(const float4*)(wap);
                    float4 w1q = *(const float4*)(wap + 4);
                    gp[nt] += f0.x * w0.x + f0.y * w0.y + f0.z * w0.z + f0.w * w0.w
                            + f1.x * w1q.x + f1.y * w1q.y + f1.z * w1q.z + f1.w * w1q.w;
                }
            }
#pragma unroll
            for (int tm = 0; tm < 8; ++tm) {
                short8 a = ldsW1[(ks * 8 + tm) * 64 + lane];
                acc1[tm][0] = __builtin_amdgcn_mfma_f32_16x16x32_bf16(a, bf[0], acc1[tm][0], 0, 0, 0);
                acc1[tm][1] = __builtin_amdgcn_mfma_f32_16x16x32_bf16(a, bf[1], acc1[tm][1], 0, 0, 0);
            }
        }
        float gate[2];
#pragma unroll
        for (int nt = 0; nt < 2; ++nt) {
            float ssum = gp[nt];
            ssum += __shfl_xor(ssum, 16);
            ssum += __shfl_xor(ssum, 32);
            gate[nt] = 1.f / (1.f + expf(-(ssum + baS)));
        }
        short8 pf[4][2];
#pragma unroll
        for (int ks2 = 0; ks2 < 4; ++ks2) {
            float4 c0 = *(const float4*)(b1v + (2 * ks2) * 16 + 4 * g);
            float4 c1 = *(const float4*)(b1v + (2 * ks2 + 1) * 16 + 4 * g);
#pragma unroll
            for (int nt = 0; nt < 2; ++nt) {
                float4 lo, hi;
                lo.x = fmaxf(acc1[2*ks2][nt][0] + c0.x, 0.f);
                lo.y = fmaxf(acc1[2*ks2][nt][1] + c0.y, 0.f);
                lo.z = fmaxf(acc1[2*ks2][nt][2] + c0.z, 0.f);
                lo.w = fmaxf(acc1[2*ks2][nt][3] + c0.w, 0.f);
                hi.x = fmaxf(acc1[2*ks2+1][nt][0] + c1.x, 0.f);
                hi.y = fmaxf(acc1[2*ks2+1][nt][1] + c1.y, 0.f);
                hi.z = fmaxf(acc1[2*ks2+1][nt][2] + c1.z, 0.f);
                hi.w = fmaxf(acc1[2*ks2+1][nt][3] + c1.w, 0.f);
                pf[ks2][nt] = pack8(lo, hi);
            }
        }
        f32x4 acc2[8][2];
#pragma unroll
        for (int tn = 0; tn < 8; ++tn)
#pragma unroll
            for (int nt = 0; nt < 2; ++nt) acc2[tn][nt] = (f32x4){0.f,0.f,0.f,0.f};
#pragma unroll
        for (int ks2 = 0; ks2 < 4; ++ks2) {
#pragma unroll
            for (int tn = 0; tn < 8; ++tn) {
                short8 ww = w2p[(ks2 * 8 + tn) * 64 + lane];
                acc2[tn][0] = __builtin_amdgcn_mfma_f32_16x16x32_bf16(pf[ks2][0], ww, acc2[tn][0], 0, 0, 0);
                acc2[tn][1] = __builtin_amdgcn_mfma_f32_16x16x32_bf16(pf[ks2][1], ww, acc2[tn][1], 0, 0, 0);
            }
        }
#pragma unroll
        for (int nt = 0; nt < 2; ++nt) {
            int nodeR[4]; float gt[4];
#pragma unroll
            for (int r = 0; r < 4; ++r) {
                nodeR[r] = __shfl(rA[nt], 4 * g + r);
                gt[r] = __shfl(gate[nt], 4 * g + r);
            }
#pragma unroll
            for (int tn = 0; tn < 8; ++tn) {
                float c2 = b2v[tn * 16 + m];
#pragma unroll
                for (int r = 0; r < 4; ++r) {
                    float vv = (acc2[tn][nt][r] + c2) * gt[r];
                    atomicAdd(outp + (long)nodeR[r] * 128 + tn * 16 + m, vv);
                }
            }
        }
    }
}

extern "C" void kernel_launch(void* const* d_in, const int* in_sizes, int n_in,
                              void* d_out, int out_size, void* d_ws, size_t ws_size,
                              hipStream_t stream) {
    const float* h    = (const float*)d_in[0];
    const int*   ei   = (const int*)d_in[1];
    const float* bond = (const float*)d_in[2];
    const float* W1   = (const float*)d_in[3];
    const float* b1   = (const float*)d_in[4];
    const float* W2   = (const float*)d_in[5];
    const float* b2   = (const float*)d_in[6];
    const float* Wa   = (const float*)d_in[7];
    const float* ba   = (const float*)d_in[8];
    float* outp = (float*)d_out;

    char* ws = (char*)d_ws;
    const size_t o_w1  = 0;            // 81920
    const size_t o_w2  = 81920;        // 32768 (w2n main / w2p fallback)
    const size_t o_hbf = 114688;       // 12,800,000
    const size_t o_cnt = 12914688;     // 200,000
    const size_t o_scn = 13114688;     // 200,000 (aliased as G after scan3)
    const size_t o_bs  = 13314688;     // 1,024
    const size_t o_bo  = 13315712;     // 1,024
    const size_t o_cur = 13316736;     // 200,000
    const size_t o_rec = 13516736;     // 12,800,000
    const size_t need  = 26316736;

    unsigned short* w1p = (unsigned short*)(ws + o_w1);
    unsigned short* w2p = (unsigned short*)(ws + o_w2);

    if (ws_size >= need) {
        unsigned short* hbf = (unsigned short*)(ws + o_hbf);
        int* cnt = (int*)(ws + o_cnt);
        int* scn = (int*)(ws + o_scn);
        int* bs  = (int*)(ws + o_bs);
        int* bo  = (int*)(ws + o_bo);
        int* cur = (int*)(ws + o_cur);
        int4* recs = (int4*)(ws + o_rec);
        float* G = (float*)(ws + o_scn);   // alias: scn dead after scan3

        hipLaunchKernelGGL(pack_weights_kernel, dim3(160), dim3(256), 0, stream, W1, W2, w1p, w2p);
        hipLaunchKernelGGL(prep_kernel, dim3(2048), dim3(256), 0, stream,
                           (const float4*)h, (ushort4*)hbf, (float4*)outp, G, cnt);
        hipLaunchKernelGGL(hist_kernel, dim3(1024), dim3(256), 0, stream, ei, cnt);
        hipLaunchKernelGGL(scan1_kernel, dim3(NB1), dim3(256), 0, stream, cnt, scn, bs);
        hipLaunchKernelGGL(scan2_kernel, dim3(1), dim3(256), 0, stream, bs, bo);
        hipLaunchKernelGGL(scan3_kernel, dim3(NB1), dim3(256), 0, stream, scn, bo, cur);
        hipLaunchKernelGGL(scatter_kernel, dim3(1024), dim3(256), 0, stream, ei, cur, recs);
        hipLaunchKernelGGL(edge_kernel_sorted, dim3(EDGE_BLOCKS), dim3(512), 0, stream,
                           hbf, recs, bond, b1, Wa, ba,
                           (const short8*)w1p, outp, G);
        hipLaunchKernelGGL(final_mfma_kernel, dim3((NN / 16 + 3) / 4), dim3(256), 0, stream,
                           h, G, b2, (const short8*)w2p, outp);
    } else {
        hipLaunchKernelGGL(pack_w1_kernel, dim3(160), dim3(256), 0, stream, W1, w1p);
        hipLaunchKernelGGL(pack_w2_kernel, dim3(64), dim3(256), 0, stream, W2, w2p);
        hipLaunchKernelGGL(copy_h_kernel, dim3(1600), dim3(256), 0, stream,
                           (const float4*)h, (float4*)outp);
        hipLaunchKernelGGL(edge_kernel_unsorted, dim3(512), dim3(512), 0, stream,
                           h, ei, bond, b1, b2, Wa, ba,
                           (const short8*)w1p, (const short8*)w2p, outp);
    }
}